// Round 6
// baseline (11978.274 us; speedup 1.0000x reference)
//
#include <hip/hip_runtime.h>
#include <stdint.h>

// SingleBandLSTM: B=64, IN=16, H=512, T=1024, 2-layer LSTM, constant input per step.
// R6: 32 fused persistent blocks x 512 threads. Each block owns 16 units of layer-0
// AND 16 units of layer-1 (layer-1 lags one step). Slot[t] = {h0[t], h1[t-1]}.
// Per step: ONE poll, ONE flag store. Lessons baked in:
//  - 32 participants (was 64): less LLC contention, half the staging traffic
//  - flags: one 64B line per block (stride-16 ints) -> no line ping-pong
//  - publish: contiguous slice [blk][b][16 units], 4B/thread, __syncthreads drains
//    (vmcnt(0) before s_barrier), then single flag store. No RMW, no buffer_inv.
//  - staging/publish via compiler-generated relaxed agent atomics (sc1, LLC-coherent;
//    R4 lesson: never feed inline-asm load outputs to compiler consumers)
//  - NEW LDS swizzle col ^= (row&15)<<6: 64 distinct 16B columns per fragment read
//    -> conflict-free ds_read_b128 (old (row&7)<<4 scheme was 8-way conflicted)

#define TSEQ 1024
#define HDIM 512
#define BATCH 64
#define RING 4
#define NBLK 32
#define GST 132   // gbuf float stride

typedef __attribute__((ext_vector_type(8))) short bf16x8;
typedef __attribute__((ext_vector_type(4))) float f32x4;
typedef __attribute__((ext_vector_type(4))) unsigned int u32x4;
typedef unsigned long long u64;

__device__ __forceinline__ unsigned short f2bf(float f) {
  union { float f; unsigned u; } v; v.f = f;
  unsigned r = v.u + 0x7FFFu + ((v.u >> 16) & 1u);   // RNE
  return (unsigned short)(r >> 16);
}
__device__ __forceinline__ float bf2f(unsigned short s) {
  union { unsigned u; float f; } v; v.u = ((unsigned)s) << 16; return v.f;
}
__device__ __forceinline__ float sigm(float x) { return 1.0f / (1.0f + __expf(-x)); }
__device__ __forceinline__ float tanh_(float x) { return 1.0f - 2.0f / (__expf(2.0f * x) + 1.0f); }

__device__ __forceinline__ u64 g_ld64(const u64* p) {
  return __hip_atomic_load(p, __ATOMIC_RELAXED, __HIP_MEMORY_SCOPE_AGENT);
}
__device__ __forceinline__ int g_ld32(const int* p) {
  return __hip_atomic_load(p, __ATOMIC_RELAXED, __HIP_MEMORY_SCOPE_AGENT);
}
__device__ __forceinline__ void g_st32(int* p, int v) {
  __hip_atomic_store(p, v, __ATOMIC_RELAXED, __HIP_MEMORY_SCOPE_AGENT);
}
__device__ __forceinline__ void g_st32u(unsigned* p, unsigned v) {
  __hip_atomic_store(p, v, __ATOMIC_RELAXED, __HIP_MEMORY_SCOPE_AGENT);
}

// Poll: lanes read flags[(lane&31)*16] (one 64B line per producer); pass when all >= tgt.
__device__ __forceinline__ void poll_ge(const int* f, int tgt, int lane) {
  const int* a = f + (lane & 31) * 16;
  while (!__all(g_ld32(a) >= tgt)) __builtin_amdgcn_s_sleep(1);
}

// Ring slice layout: [32 blk][64 b][16 units bf16] (2KB/blk, 64KB total per half).
// LDS layout: row b (1KB of 512 units), byte col c stored at c ^ ((b&15)<<6).
__device__ __forceinline__ void stage_two(char* ldsA, const char* srcA,
                                          char* ldsB, const char* srcB, int tid) {
  u64 la[8], ha[8], lb[8], hb[8];
  #pragma unroll
  for (int i = 0; i < 8; ++i) {
    const u64* sa = (const u64*)(srcA + (size_t)(tid + i * 512) * 16);
    la[i] = g_ld64(sa);
    ha[i] = g_ld64(sa + 1);
  }
  #pragma unroll
  for (int i = 0; i < 8; ++i) {
    const u64* sb = (const u64*)(srcB + (size_t)(tid + i * 512) * 16);
    lb[i] = g_ld64(sb);
    hb[i] = g_ld64(sb + 1);
  }
  #pragma unroll
  for (int i = 0; i < 8; ++i) {
    int q = tid + i * 512;
    int b = (q >> 1) & 63;
    int col = (((q >> 7) << 5) | ((q & 1) << 4)) ^ ((b & 15) << 6);
    int off = b * 1024 + col;
    u32x4 va, vb;
    ((u64*)&va)[0] = la[i]; ((u64*)&va)[1] = ha[i];
    ((u64*)&vb)[0] = lb[i]; ((u64*)&vb)[1] = hb[i];
    *(u32x4*)(ldsA + off) = va;
    *(u32x4*)(ldsB + off) = vb;
  }
}
__device__ __forceinline__ void stage_one(char* lds, const char* src, int tid) {
  u64 lo[8], hi[8];
  #pragma unroll
  for (int i = 0; i < 8; ++i) {
    const u64* s = (const u64*)(src + (size_t)(tid + i * 512) * 16);
    lo[i] = g_ld64(s);
    hi[i] = g_ld64(s + 1);
  }
  #pragma unroll
  for (int i = 0; i < 8; ++i) {
    int q = tid + i * 512;
    int b = (q >> 1) & 63;
    int col = (((q >> 7) << 5) | ((q & 1) << 4)) ^ ((b & 15) << 6);
    u32x4 v;
    ((u64*)&v)[0] = lo[i];
    ((u64*)&v)[1] = hi[i];
    *(u32x4*)(lds + b * 1024 + col) = v;
  }
}
__device__ __forceinline__ void zerobuf(char* lds, int tid) {
  u32x4 z = {0u, 0u, 0u, 0u};
  #pragma unroll
  for (int i = 0; i < 8; ++i)
    *(u32x4*)(lds + (size_t)(tid + i * 512) * 16) = z;
}

// ---------------- precompute kernels ----------------
__global__ void k_fc_in(const float* __restrict__ x, const float* __restrict__ w_in,
                        const float* __restrict__ b_in, float* __restrict__ h_in) {
  int b = blockIdx.x;      // 64
  int j = threadIdx.x;     // 512
  float acc = b_in[j];
  #pragma unroll
  for (int i = 0; i < 16; ++i) acc += x[b * 16 + i] * w_in[j * 16 + i];
  h_in[b * HDIM + j] = acc;
}

__global__ __launch_bounds__(512, 1)
void k_xg0(const float* __restrict__ h_in, const float* __restrict__ w_ih0,
           const float* __restrict__ b_ih0, const float* __restrict__ b_hh0,
           float* __restrict__ xg0) {
  __shared__ float hbuf[64 * 516];
  __shared__ float wbuf[8 * 520];
  int r0 = blockIdx.x * 8;           // 256 blocks x 8 rows = 2048 gate rows
  int tid = threadIdx.x;
  for (int i = 0; i < 64; ++i) {
    int c = tid + i * 512;
    hbuf[(c >> 9) * 516 + (c & 511)] = h_in[c];
  }
  for (int i = 0; i < 8; ++i) {
    int c = tid + i * 512;
    wbuf[(c >> 9) * 520 + (c & 511)] = w_ih0[(size_t)r0 * HDIM + c];
  }
  __syncthreads();
  int b = tid >> 3, rl = tid & 7;
  float acc = 0.f;
  for (int k = 0; k < 512; ++k) acc += hbuf[b * 516 + k] * wbuf[rl * 520 + k];
  int r = r0 + rl;
  xg0[(size_t)b * 2048 + r] = acc + b_ih0[r] + b_hh0[r];
}

// ---------------- fused persistent recurrence kernel ----------------
__global__ __launch_bounds__(512, 1)
void lstm_persist(const float* __restrict__ w_hh0,
                  const float* __restrict__ w_ih1,
                  const float* __restrict__ w_hh1,
                  const float* __restrict__ b_ih1,
                  const float* __restrict__ b_hh1,
                  const float* __restrict__ w_out,
                  const float* __restrict__ b_out,
                  const float* __restrict__ xg0,
                  unsigned short* __restrict__ ring,   // RING x {h0 64KB, h1 64KB}
                  int* __restrict__ flags,             // NBLK x 16 ints (64B stride)
                  float* __restrict__ out) {
  __shared__ __align__(16) char hAbuf[65536];   // h0[t-1]; gbuf aliases after B3
  __shared__ __align__(16) char hBbuf[65536];   // h1[t-2]
  __shared__ float wout_s[HDIM];
  char* hAc = hAbuf;
  char* hBc = hBbuf;
  float* gbuf = (float*)hAbuf;                  // [64 b][GST] rows; cols 0-63 L0, 64-127 L1

  const int tid = threadIdx.x;
  const int blk = blockIdx.x;                   // 0..31
  const int wave = tid >> 6, lane = tid & 63;
  const int ln15 = lane & 15, lg = lane >> 4;
  const bool isL1w = (wave >= 4);
  const int ntL = wave & 3;

  const int n_local = ntL * 16 + ln15;          // 0..63 within layer: unit*4+gate
  const int grow = (n_local & 3) * HDIM + blk * 16 + (n_local >> 2);

  const int rb = ln15 * 1024;                   // A-frag row base (per m add m*16KB)
  const int xs = ln15 << 6;                     // conflict-free swizzle, static per lane

  wout_s[tid] = w_out[tid];
  const float bout = b_out[0];

  // ---- weight fragments (fp32 -> bf16): wA = (L0: w_hh0 | L1: w_ih1), wB = w_hh1 ----
  bf16x8 wA[16], wB[16];
  {
    const float* W1 = (isL1w ? w_ih1 : w_hh0) + (size_t)grow * HDIM;
    #pragma unroll
    for (int kt = 0; kt < 16; ++kt) {
      const float* s = W1 + kt * 32 + lg * 8;
      bf16x8 r;
      #pragma unroll
      for (int e = 0; e < 8; ++e) r[e] = (short)f2bf(s[e]);
      wA[kt] = r;
    }
  }
  if (isL1w) {
    const float* W2 = w_hh1 + (size_t)grow * HDIM;
    #pragma unroll
    for (int kt = 0; kt < 16; ++kt) {
      const float* s = W2 + kt * 32 + lg * 8;
      bf16x8 r;
      #pragma unroll
      for (int e = 0; e < 8; ++e) r[e] = (short)f2bf(s[e]);
      wB[kt] = r;
    }
  }

  // ---- accumulator init: xg0 fragments (L0 waves) or bias (L1 waves) ----
  f32x4 i0, i1, i2, i3;
  if (!isL1w) {
    #pragma unroll
    for (int r = 0; r < 4; ++r) {
      i0[r] = xg0[(size_t)(lg * 4 + r) * 2048 + grow];
      i1[r] = xg0[(size_t)(16 + lg * 4 + r) * 2048 + grow];
      i2[r] = xg0[(size_t)(32 + lg * 4 + r) * 2048 + grow];
      i3[r] = xg0[(size_t)(48 + lg * 4 + r) * 2048 + grow];
    }
  } else {
    float bv = b_ih1[grow] + b_hh1[grow];
    #pragma unroll
    for (int r = 0; r < 4; ++r) { i0[r] = bv; i1[r] = bv; i2[r] = bv; i3[r] = bv; }
  }

  // ---- per-thread nonlinearity ownership: batch b, units uc & uc+1 (both layers) ----
  const int pb = tid >> 3, pk = tid & 7, uc = pk * 2;
  float c0A = 0.f, c0B = 0.f, c1A = 0.f, c1B = 0.f;

  const int ob = tid >> 2, oseg = tid & 3;       // out-dot (tid<256)
  const int oxs = (ob & 15) << 6;

  for (int t = 0; t <= TSEQ; ++t) {
    // ---- phase 1: wait + stage slot[t-1] = {h0[t-1], h1[t-2]} ----
    if (t > 0) {
      if (wave == 0) poll_ge(flags, t, lane);
      __syncthreads();                                          // B1
      const char* slot = (const char*)ring + (size_t)((t - 1) & (RING - 1)) * 131072;
      stage_two(hAc, slot, hBc, slot + 65536, tid);
    } else {
      __syncthreads();                                          // B1 (uniform)
      zerobuf(hAc, tid);
      zerobuf(hBc, tid);
    }
    __syncthreads();                                            // B2

    // ---- phase 2: MFMA (accs persist across B3) ----
    f32x4 a0, a1, a2, a3;
    if (!isL1w) {
      if (t < TSEQ) {
        a0 = i0; a1 = i1; a2 = i2; a3 = i3;
        #pragma unroll
        for (int kt = 0; kt < 16; ++kt) {
          const int co = (kt * 64 + lg * 16) ^ xs;
          bf16x8 h0 = *(const bf16x8*)(hAc + rb + co);
          bf16x8 h1 = *(const bf16x8*)(hAc + 16384 + rb + co);
          bf16x8 h2 = *(const bf16x8*)(hAc + 32768 + rb + co);
          bf16x8 h3 = *(const bf16x8*)(hAc + 49152 + rb + co);
          a0 = __builtin_amdgcn_mfma_f32_16x16x32_bf16(h0, wA[kt], a0, 0, 0, 0);
          a1 = __builtin_amdgcn_mfma_f32_16x16x32_bf16(h1, wA[kt], a1, 0, 0, 0);
          a2 = __builtin_amdgcn_mfma_f32_16x16x32_bf16(h2, wA[kt], a2, 0, 0, 0);
          a3 = __builtin_amdgcn_mfma_f32_16x16x32_bf16(h3, wA[kt], a3, 0, 0, 0);
        }
      }
      // out[:, t-2] from hB = h1[t-2] (light waves; overlaps L1 waves' MFMA tail)
      if (t >= 2 && tid < 256) {
        float od = 0.f;
        #pragma unroll
        for (int j = 0; j < 16; ++j) {
          const int c = (j * 4 + oseg) * 16;
          bf16x8 hv = *(const bf16x8*)(hBc + ob * 1024 + (c ^ oxs));
          const float* wo = &wout_s[c >> 1];
          #pragma unroll
          for (int e = 0; e < 8; ++e) od += bf2f((unsigned short)hv[e]) * wo[e];
        }
        od += __shfl_xor(od, 1);
        od += __shfl_xor(od, 2);
        if (oseg == 0) out[ob * TSEQ + (t - 2)] = od + bout;
      }
    } else {
      if (t >= 1) {
        a0 = i0; a1 = i1; a2 = i2; a3 = i3;
        f32x4 d0 = {0,0,0,0}, d1 = {0,0,0,0}, d2 = {0,0,0,0}, d3 = {0,0,0,0};
        #pragma unroll
        for (int kt = 0; kt < 16; ++kt) {
          const int co = (kt * 64 + lg * 16) ^ xs;
          bf16x8 pA0 = *(const bf16x8*)(hAc + rb + co);
          bf16x8 pA1 = *(const bf16x8*)(hAc + 16384 + rb + co);
          bf16x8 pA2 = *(const bf16x8*)(hAc + 32768 + rb + co);
          bf16x8 pA3 = *(const bf16x8*)(hAc + 49152 + rb + co);
          bf16x8 pB0 = *(const bf16x8*)(hBc + rb + co);
          bf16x8 pB1 = *(const bf16x8*)(hBc + 16384 + rb + co);
          bf16x8 pB2 = *(const bf16x8*)(hBc + 32768 + rb + co);
          bf16x8 pB3 = *(const bf16x8*)(hBc + 49152 + rb + co);
          a0 = __builtin_amdgcn_mfma_f32_16x16x32_bf16(pA0, wA[kt], a0, 0, 0, 0);
          a1 = __builtin_amdgcn_mfma_f32_16x16x32_bf16(pA1, wA[kt], a1, 0, 0, 0);
          a2 = __builtin_amdgcn_mfma_f32_16x16x32_bf16(pA2, wA[kt], a2, 0, 0, 0);
          a3 = __builtin_amdgcn_mfma_f32_16x16x32_bf16(pA3, wA[kt], a3, 0, 0, 0);
          d0 = __builtin_amdgcn_mfma_f32_16x16x32_bf16(pB0, wB[kt], d0, 0, 0, 0);
          d1 = __builtin_amdgcn_mfma_f32_16x16x32_bf16(pB1, wB[kt], d1, 0, 0, 0);
          d2 = __builtin_amdgcn_mfma_f32_16x16x32_bf16(pB2, wB[kt], d2, 0, 0, 0);
          d3 = __builtin_amdgcn_mfma_f32_16x16x32_bf16(pB3, wB[kt], d3, 0, 0, 0);
        }
        a0 += d0; a1 += d1; a2 += d2; a3 += d3;
      }
    }
    __syncthreads();                                            // B3: hA dead -> gbuf

    // ---- phase 3: gate staging into gbuf (aliases hA) ----
    bool wr = isL1w ? (t >= 1) : (t < TSEQ);
    if (wr) {
      const int cbase = (isL1w ? 64 : 0) + n_local;
      #pragma unroll
      for (int r = 0; r < 4; ++r) {
        gbuf[(lg * 4 + r) * GST + cbase] = a0[r];
        gbuf[(16 + lg * 4 + r) * GST + cbase] = a1[r];
        gbuf[(32 + lg * 4 + r) * GST + cbase] = a2[r];
        gbuf[(48 + lg * 4 + r) * GST + cbase] = a3[r];
      }
    }
    __syncthreads();                                            // B4

    // ---- phase 4: nonlinearity + publish slot[t] ----
    unsigned pk0 = 0, pk1 = 0;
    if (t < TSEQ) {
      f32x4 gA = *(const f32x4*)&gbuf[pb * GST + uc * 4];
      f32x4 gB = *(const f32x4*)&gbuf[pb * GST + uc * 4 + 4];
      float ii = sigm(gA[0]), ff = sigm(gA[1]), zz = tanh_(gA[2]), oo = sigm(gA[3]);
      c0A = ff * c0A + ii * zz;
      float h0a = oo * tanh_(c0A);
      ii = sigm(gB[0]); ff = sigm(gB[1]); zz = tanh_(gB[2]); oo = sigm(gB[3]);
      c0B = ff * c0B + ii * zz;
      float h0b = oo * tanh_(c0B);
      pk0 = (unsigned)f2bf(h0a) | ((unsigned)f2bf(h0b) << 16);
    }
    if (t >= 1) {
      f32x4 gA = *(const f32x4*)&gbuf[pb * GST + 64 + uc * 4];
      f32x4 gB = *(const f32x4*)&gbuf[pb * GST + 64 + uc * 4 + 4];
      float ii = sigm(gA[0]), ff = sigm(gA[1]), zz = tanh_(gA[2]), oo = sigm(gA[3]);
      c1A = ff * c1A + ii * zz;
      float h1a = oo * tanh_(c1A);
      ii = sigm(gB[0]); ff = sigm(gB[1]); zz = tanh_(gB[2]); oo = sigm(gB[3]);
      c1B = ff * c1B + ii * zz;
      float h1b = oo * tanh_(c1B);
      pk1 = (unsigned)f2bf(h1a) | ((unsigned)f2bf(h1b) << 16);
    }
    {
      char* slotw = (char*)ring + (size_t)(t & (RING - 1)) * 131072;
      const int so = blk * 2048 + pb * 32 + pk * 4;
      g_st32u((unsigned*)(slotw + so), pk0);
      g_st32u((unsigned*)(slotw + 65536 + so), pk1);
    }
    __syncthreads();   // B5: per-wave vmcnt(0) before s_barrier -> stores at LLC
    if (tid == 0) g_st32(&flags[blk * 16], t + 1);
  }

  // ---- epilogue: out[:, T-1] from h1[T-1] in slot[TSEQ] ----
  if (wave == 0) poll_ge(flags, TSEQ + 1, lane);
  __syncthreads();
  stage_one(hBc, (const char*)ring + (size_t)(TSEQ & (RING - 1)) * 131072 + 65536, tid);
  __syncthreads();
  if (tid < 256) {
    float od = 0.f;
    #pragma unroll
    for (int j = 0; j < 16; ++j) {
      const int c = (j * 4 + oseg) * 16;
      bf16x8 hv = *(const bf16x8*)(hBc + ob * 1024 + (c ^ oxs));
      const float* wo = &wout_s[c >> 1];
      #pragma unroll
      for (int e = 0; e < 8; ++e) od += bf2f((unsigned short)hv[e]) * wo[e];
    }
    od += __shfl_xor(od, 1);
    od += __shfl_xor(od, 2);
    if (oseg == 0) out[ob * TSEQ + (TSEQ - 1)] = od + bout;
  }
}

extern "C" void kernel_launch(void* const* d_in, const int* in_sizes, int n_in,
                              void* d_out, int out_size, void* d_ws, size_t ws_size,
                              hipStream_t stream) {
  (void)in_sizes; (void)n_in; (void)out_size; (void)ws_size;
  const float* x     = (const float*)d_in[0];
  const float* w_in  = (const float*)d_in[1];
  const float* b_in  = (const float*)d_in[2];
  const float* w_ih0 = (const float*)d_in[3];
  const float* w_hh0 = (const float*)d_in[4];
  const float* b_ih0 = (const float*)d_in[5];
  const float* b_hh0 = (const float*)d_in[6];
  const float* w_ih1 = (const float*)d_in[7];
  const float* w_hh1 = (const float*)d_in[8];
  const float* b_ih1 = (const float*)d_in[9];
  const float* b_hh1 = (const float*)d_in[10];
  const float* w_out = (const float*)d_in[11];
  const float* b_out = (const float*)d_in[12];

  char* ws = (char*)d_ws;
  unsigned short* ring = (unsigned short*)(ws + 0);             // 4 * 128KB = 512KB
  float* xg0   = (float*)(ws + 524288);                         // 512KB
  float* h_in  = (float*)(ws + 1048576);                        // 128KB
  int*   flags = (int*)(ws + 1179648);                          // 32 * 64B = 2KB

  hipMemsetAsync(flags, 0, NBLK * 16 * sizeof(int), stream);
  k_fc_in<<<64, 512, 0, stream>>>(x, w_in, b_in, h_in);
  k_xg0<<<256, 512, 0, stream>>>(h_in, w_ih0, b_ih0, b_hh0, xg0);
  lstm_persist<<<NBLK, 512, 0, stream>>>(w_hh0, w_ih1, w_hh1, b_ih1, b_hh1,
                                         w_out, b_out, xg0, ring,
                                         flags, (float*)d_out);
}

// Round 7
// 11160.973 us; speedup vs baseline: 1.0732x; 1.0732x over previous
//
#include <hip/hip_runtime.h>
#include <stdint.h>

// SingleBandLSTM: B=64, IN=16, H=512, T=1024, 2-layer LSTM, constant input per step.
// R7: 32 fused persistent blocks x 512 threads (each owns 16 units of L0 + 16 of L1,
// L1 lags one step). Slot[t] = {h0[t], h1[t-1]} published during iter t.
// Key fixes vs R6:
//  - flags via atomic fetch_add RMW on per-block private 64B lines: RMW executes at
//    the LLC -> immediately visible to pollers (R2, the best round, used RMW; the
//    plain-store rounds R5/R6 regressed -> lazy store visibility was the chain cost)
//  - LDS swizzle reverted to ((row&7)<<4) on byte col (bits[6:4] = bank-slot bits);
//    R6's (b&15)<<6 only touched bit6 -> 16-way staging-write conflicts (1.38e8)
//  - 5 barriers/step: MFMA accs held in regs across B3; gbuf/hpk ALIAS dead hA;
//    h0 and h1 publishes run in parallel (waves 0 and 1) at the step tail.
// Kept: coalesced u64 relaxed-agent staging loads (compiler-generated waitcnts,
// R4 lesson), no buffer_inv (R3 lesson), no shared-counter contention (R1 lesson).

#define TSEQ 1024
#define HDIM 512
#define BATCH 64
#define NBLK 32
#define GST 68   // gbuf float stride (68*4 = 272B, 16B-aligned rows, bank-shift 4)

typedef __attribute__((ext_vector_type(8))) short bf16x8;
typedef __attribute__((ext_vector_type(4))) float f32x4;
typedef __attribute__((ext_vector_type(4))) unsigned int u32x4;
typedef unsigned long long u64;

__device__ __forceinline__ unsigned short f2bf(float f) {
  union { float f; unsigned u; } v; v.f = f;
  unsigned r = v.u + 0x7FFFu + ((v.u >> 16) & 1u);   // RNE
  return (unsigned short)(r >> 16);
}
__device__ __forceinline__ float bf2f(unsigned short s) {
  union { unsigned u; float f; } v; v.u = ((unsigned)s) << 16; return v.f;
}
__device__ __forceinline__ float sigm(float x) { return 1.0f / (1.0f + __expf(-x)); }
__device__ __forceinline__ float tanh_(float x) { return 1.0f - 2.0f / (__expf(2.0f * x) + 1.0f); }

__device__ __forceinline__ u64 g_ld64(const u64* p) {
  return __hip_atomic_load(p, __ATOMIC_RELAXED, __HIP_MEMORY_SCOPE_AGENT);
}
__device__ __forceinline__ void g_st64(u64* p, u64 v) {
  __hip_atomic_store(p, v, __ATOMIC_RELAXED, __HIP_MEMORY_SCOPE_AGENT);
}
__device__ __forceinline__ int g_ld32(const int* p) {
  return __hip_atomic_load(p, __ATOMIC_RELAXED, __HIP_MEMORY_SCOPE_AGENT);
}

// Stage 64KB ring half [32 srcblk][64 b][16 units bf16] -> LDS [b][512u] with byte-col
// XOR ((b&7)<<4). Quad q (16B): producer q>>7, batch (q>>1)&63, col16 = (q>>7)*2+(q&1).
__device__ __forceinline__ void stage_one(char* lds, const char* src, int tid) {
  u64 lo[8], hi[8];
  #pragma unroll
  for (int i = 0; i < 8; ++i) {
    const u64* s = (const u64*)(src + (size_t)(tid + i * 512) * 16);
    lo[i] = g_ld64(s);
    hi[i] = g_ld64(s + 1);
  }
  #pragma unroll
  for (int i = 0; i < 8; ++i) {
    int q = tid + i * 512;
    int b = (q >> 1) & 63;
    int col = (((q >> 7) << 5) | ((q & 1) << 4)) ^ ((b & 7) << 4);
    u32x4 v;
    ((u64*)&v)[0] = lo[i];
    ((u64*)&v)[1] = hi[i];
    *(u32x4*)(lds + b * 1024 + col) = v;
  }
}
__device__ __forceinline__ void zerobuf(char* lds, int tid) {
  u32x4 z = {0u, 0u, 0u, 0u};
  #pragma unroll
  for (int i = 0; i < 8; ++i)
    *(u32x4*)(lds + (size_t)(tid + i * 512) * 16) = z;
}

// ---------------- precompute kernels ----------------
__global__ void k_fc_in(const float* __restrict__ x, const float* __restrict__ w_in,
                        const float* __restrict__ b_in, float* __restrict__ h_in) {
  int b = blockIdx.x;      // 64
  int j = threadIdx.x;     // 512
  float acc = b_in[j];
  #pragma unroll
  for (int i = 0; i < 16; ++i) acc += x[b * 16 + i] * w_in[j * 16 + i];
  h_in[b * HDIM + j] = acc;
}

__global__ __launch_bounds__(512, 1)
void k_xg0(const float* __restrict__ h_in, const float* __restrict__ w_ih0,
           const float* __restrict__ b_ih0, const float* __restrict__ b_hh0,
           float* __restrict__ xg0) {
  __shared__ float hbuf[64 * 516];
  __shared__ float wbuf[8 * 520];
  int r0 = blockIdx.x * 8;           // 256 blocks x 8 rows = 2048 gate rows
  int tid = threadIdx.x;
  for (int i = 0; i < 64; ++i) {
    int c = tid + i * 512;
    hbuf[(c >> 9) * 516 + (c & 511)] = h_in[c];
  }
  for (int i = 0; i < 8; ++i) {
    int c = tid + i * 512;
    wbuf[(c >> 9) * 520 + (c & 511)] = w_ih0[(size_t)r0 * HDIM + c];
  }
  __syncthreads();
  int b = tid >> 3, rl = tid & 7;
  float acc = 0.f;
  for (int k = 0; k < 512; ++k) acc += hbuf[b * 516 + k] * wbuf[rl * 520 + k];
  int r = r0 + rl;
  xg0[(size_t)b * 2048 + r] = acc + b_ih0[r] + b_hh0[r];
}

// ---------------- fused persistent recurrence kernel ----------------
__global__ __launch_bounds__(512, 1)
void lstm_persist(const float* __restrict__ w_hh0,
                  const float* __restrict__ w_ih1,
                  const float* __restrict__ w_hh1,
                  const float* __restrict__ b_ih1,
                  const float* __restrict__ b_hh1,
                  const float* __restrict__ w_out,
                  const float* __restrict__ b_out,
                  const float* __restrict__ xg0,
                  unsigned short* __restrict__ ring,   // 4 slots x {h0 64KB, h1 64KB}
                  int* __restrict__ flags,             // f0: [blk*16]; f1: [512+blk*16]
                  float* __restrict__ out) {
  __shared__ __align__(16) char hA[65536];   // h0[t-1]; gbufs/hpk alias after B3
  __shared__ __align__(16) char hB[65536];   // h1[t-2]
  __shared__ float wout_s[HDIM];
  float* gbuf0 = (float*)hA;                       // 64 x GST f32 (17408B)
  float* gbuf1 = (float*)(hA + 17408);             // 64 x GST f32
  unsigned short* hpk0 = (unsigned short*)(hA + 34816);  // [64b][16u] bf16 (2KB)
  unsigned short* hpk1 = (unsigned short*)(hA + 36864);  // 2KB
  char* ringc = (char*)ring;

  const int tid = threadIdx.x;
  const int blk = blockIdx.x;                   // 0..31
  const int wave = tid >> 6, lane = tid & 63;
  const int ln15 = lane & 15, lg = lane >> 4;
  const bool isL1w = (wave >= 4);
  const int ntL = wave & 3;

  const int n_local = ntL * 16 + ln15;          // 0..63 within layer: unit*4+gate
  const int grow = (n_local & 3) * HDIM + blk * 16 + (n_local >> 2);

  const int xs = (ln15 & 7) << 4;               // MFMA A-frag read swizzle

  int* f0 = &flags[blk * 16];
  int* f1 = &flags[512 + blk * 16];

  wout_s[tid] = w_out[tid];
  const float bout = b_out[0];

  // ---- weight fragments (fp32 -> bf16): wA = (L0: w_hh0 | L1: w_ih1), wB = w_hh1 ----
  bf16x8 wA[16], wB[16];
  {
    const float* W1 = (isL1w ? w_ih1 : w_hh0) + (size_t)grow * HDIM;
    #pragma unroll
    for (int kt = 0; kt < 16; ++kt) {
      const float* s = W1 + kt * 32 + lg * 8;
      bf16x8 r;
      #pragma unroll
      for (int e = 0; e < 8; ++e) r[e] = (short)f2bf(s[e]);
      wA[kt] = r;
    }
  }
  if (isL1w) {
    const float* W2 = w_hh1 + (size_t)grow * HDIM;
    #pragma unroll
    for (int kt = 0; kt < 16; ++kt) {
      const float* s = W2 + kt * 32 + lg * 8;
      bf16x8 r;
      #pragma unroll
      for (int e = 0; e < 8; ++e) r[e] = (short)f2bf(s[e]);
      wB[kt] = r;
    }
  }

  // ---- accumulator init: xg0 fragments (L0 waves) or bias (L1 waves) ----
  f32x4 i0, i1, i2, i3;
  if (!isL1w) {
    #pragma unroll
    for (int r = 0; r < 4; ++r) {
      i0[r] = xg0[(size_t)(lg * 4 + r) * 2048 + grow];
      i1[r] = xg0[(size_t)(16 + lg * 4 + r) * 2048 + grow];
      i2[r] = xg0[(size_t)(32 + lg * 4 + r) * 2048 + grow];
      i3[r] = xg0[(size_t)(48 + lg * 4 + r) * 2048 + grow];
    }
  } else {
    float bv = b_ih1[grow] + b_hh1[grow];
    #pragma unroll
    for (int r = 0; r < 4; ++r) { i0[r] = bv; i1[r] = bv; i2[r] = bv; i3[r] = bv; }
  }

  // per-thread nonlinearity ownership: batch pb, units uc,uc+1 (both layers)
  const int pb = tid >> 3, uq = tid & 7, uc = uq * 2;
  float c0A = 0.f, c0B = 0.f, c1A = 0.f, c1B = 0.f;

  const int ob = tid >> 2, oseg = tid & 3;       // out-dot (tid<256)
  const int oxs = (ob & 7) << 4;

  for (int t = 0; t <= TSEQ; ++t) {
    // ---- P1: poll (f0 >= t, f1 >= t-1), per-block private lines ----
    if (t > 0 && wave == 0) {
      const int* fp = (lane < 32) ? &flags[lane * 16] : &flags[512 + (lane & 31) * 16];
      const int tgt = (lane < 32) ? t : (t - 1);
      while (!__all(g_ld32(fp) >= tgt)) __builtin_amdgcn_s_sleep(1);
    }
    __syncthreads();                                            // B1

    // ---- P2: stage slot[t-1] = {h0[t-1], h1[t-2]} ----
    if (t > 0) {
      const char* slot = ringc + (size_t)((t - 1) & 3) * 131072;
      stage_one(hA, slot, tid);
      if (t >= 2) stage_one(hB, slot + 65536, tid);
      else        zerobuf(hB, tid);
    } else {
      zerobuf(hA, tid);
      zerobuf(hB, tid);
    }
    __syncthreads();                                            // B2

    // ---- P3: MFMA (accs in regs) + out-dot on L0 waves ----
    f32x4 a0, a1, a2, a3;
    if (!isL1w) {
      if (t < TSEQ) {
        a0 = i0; a1 = i1; a2 = i2; a3 = i3;
        #pragma unroll
        for (int kt = 0; kt < 16; ++kt) {
          const int co = (kt * 64 + lg * 16) ^ xs;
          bf16x8 h0 = *(const bf16x8*)(hA + ln15 * 1024 + co);
          bf16x8 h1 = *(const bf16x8*)(hA + 16384 + ln15 * 1024 + co);
          bf16x8 h2 = *(const bf16x8*)(hA + 32768 + ln15 * 1024 + co);
          bf16x8 h3 = *(const bf16x8*)(hA + 49152 + ln15 * 1024 + co);
          a0 = __builtin_amdgcn_mfma_f32_16x16x32_bf16(h0, wA[kt], a0, 0, 0, 0);
          a1 = __builtin_amdgcn_mfma_f32_16x16x32_bf16(h1, wA[kt], a1, 0, 0, 0);
          a2 = __builtin_amdgcn_mfma_f32_16x16x32_bf16(h2, wA[kt], a2, 0, 0, 0);
          a3 = __builtin_amdgcn_mfma_f32_16x16x32_bf16(h3, wA[kt], a3, 0, 0, 0);
        }
      }
      if (t >= 2) {   // out[:, t-2] from hB = h1[t-2]
        float od = 0.f;
        #pragma unroll
        for (int j = 0; j < 16; ++j) {
          const int c = (j * 4 + oseg) * 16;
          bf16x8 hv = *(const bf16x8*)(hB + ob * 1024 + (c ^ oxs));
          const float* wo = &wout_s[c >> 1];
          #pragma unroll
          for (int e = 0; e < 8; ++e) od += bf2f((unsigned short)hv[e]) * wo[e];
        }
        od += __shfl_xor(od, 1);
        od += __shfl_xor(od, 2);
        if (oseg == 0) out[ob * TSEQ + (t - 2)] = od + bout;
      }
    } else {
      if (t >= 1) {
        a0 = i0; a1 = i1; a2 = i2; a3 = i3;
        f32x4 d0 = {0,0,0,0}, d1 = {0,0,0,0}, d2 = {0,0,0,0}, d3 = {0,0,0,0};
        #pragma unroll
        for (int kt = 0; kt < 16; ++kt) {
          const int co = (kt * 64 + lg * 16) ^ xs;
          bf16x8 pA0 = *(const bf16x8*)(hA + ln15 * 1024 + co);
          bf16x8 pA1 = *(const bf16x8*)(hA + 16384 + ln15 * 1024 + co);
          bf16x8 pA2 = *(const bf16x8*)(hA + 32768 + ln15 * 1024 + co);
          bf16x8 pA3 = *(const bf16x8*)(hA + 49152 + ln15 * 1024 + co);
          bf16x8 pB0 = *(const bf16x8*)(hB + ln15 * 1024 + co);
          bf16x8 pB1 = *(const bf16x8*)(hB + 16384 + ln15 * 1024 + co);
          bf16x8 pB2 = *(const bf16x8*)(hB + 32768 + ln15 * 1024 + co);
          bf16x8 pB3 = *(const bf16x8*)(hB + 49152 + ln15 * 1024 + co);
          a0 = __builtin_amdgcn_mfma_f32_16x16x32_bf16(pA0, wA[kt], a0, 0, 0, 0);
          a1 = __builtin_amdgcn_mfma_f32_16x16x32_bf16(pA1, wA[kt], a1, 0, 0, 0);
          a2 = __builtin_amdgcn_mfma_f32_16x16x32_bf16(pA2, wA[kt], a2, 0, 0, 0);
          a3 = __builtin_amdgcn_mfma_f32_16x16x32_bf16(pA3, wA[kt], a3, 0, 0, 0);
          d0 = __builtin_amdgcn_mfma_f32_16x16x32_bf16(pB0, wB[kt], d0, 0, 0, 0);
          d1 = __builtin_amdgcn_mfma_f32_16x16x32_bf16(pB1, wB[kt], d1, 0, 0, 0);
          d2 = __builtin_amdgcn_mfma_f32_16x16x32_bf16(pB2, wB[kt], d2, 0, 0, 0);
          d3 = __builtin_amdgcn_mfma_f32_16x16x32_bf16(pB3, wB[kt], d3, 0, 0, 0);
        }
        a0 += d0; a1 += d1; a2 += d2; a3 += d3;
      }
    }
    __syncthreads();               // B3: hA/hB reads done -> gbufs/hpk alias hA

    // ---- P4: gate staging ----
    {
      const bool wr = isL1w ? (t >= 1) : (t < TSEQ);
      if (wr) {
        float* gb = isL1w ? gbuf1 : gbuf0;
        #pragma unroll
        for (int r = 0; r < 4; ++r) {
          gb[(lg * 4 + r) * GST + n_local] = a0[r];
          gb[(16 + lg * 4 + r) * GST + n_local] = a1[r];
          gb[(32 + lg * 4 + r) * GST + n_local] = a2[r];
          gb[(48 + lg * 4 + r) * GST + n_local] = a3[r];
        }
      }
    }
    __syncthreads();                                            // B4

    // ---- P5: nonlinearity -> hpk ----
    if (t < TSEQ) {
      f32x4 gA = *(const f32x4*)&gbuf0[pb * GST + uc * 4];
      f32x4 gB = *(const f32x4*)&gbuf0[pb * GST + uc * 4 + 4];
      float ii = sigm(gA[0]), ff = sigm(gA[1]), zz = tanh_(gA[2]), oo = sigm(gA[3]);
      c0A = ff * c0A + ii * zz;
      float ha = oo * tanh_(c0A);
      ii = sigm(gB[0]); ff = sigm(gB[1]); zz = tanh_(gB[2]); oo = sigm(gB[3]);
      c0B = ff * c0B + ii * zz;
      float hb = oo * tanh_(c0B);
      *(unsigned*)&hpk0[pb * 16 + uc] = (unsigned)f2bf(ha) | ((unsigned)f2bf(hb) << 16);
    }
    if (t >= 1) {
      f32x4 gA = *(const f32x4*)&gbuf1[pb * GST + uc * 4];
      f32x4 gB = *(const f32x4*)&gbuf1[pb * GST + uc * 4 + 4];
      float ii = sigm(gA[0]), ff = sigm(gA[1]), zz = tanh_(gA[2]), oo = sigm(gA[3]);
      c1A = ff * c1A + ii * zz;
      float ha = oo * tanh_(c1A);
      ii = sigm(gB[0]); ff = sigm(gB[1]); zz = tanh_(gB[2]); oo = sigm(gB[3]);
      c1B = ff * c1B + ii * zz;
      float hb = oo * tanh_(c1B);
      *(unsigned*)&hpk1[pb * 16 + uc] = (unsigned)f2bf(ha) | ((unsigned)f2bf(hb) << 16);
    }
    __syncthreads();                                            // B5

    // ---- P6: parallel publishes (waves 0 and 1), drain, RMW flag ----
    if (wave == 0 && t < TSEQ) {
      const u64* s = (const u64*)(hpk0 + lane * 16);
      u64 v0 = s[0], v1 = s[1], v2 = s[2], v3 = s[3];
      u64* d = (u64*)(ringc + (size_t)(t & 3) * 131072 + blk * 2048 + lane * 32);
      g_st64(d + 0, v0); g_st64(d + 1, v1); g_st64(d + 2, v2); g_st64(d + 3, v3);
      asm volatile("s_waitcnt vmcnt(0)" ::: "memory");
      __builtin_amdgcn_sched_barrier(0);
      if (lane == 0)
        __hip_atomic_fetch_add(f0, 1, __ATOMIC_RELAXED, __HIP_MEMORY_SCOPE_AGENT);
    }
    if (wave == 1 && t >= 1) {
      const u64* s = (const u64*)(hpk1 + lane * 16);
      u64 v0 = s[0], v1 = s[1], v2 = s[2], v3 = s[3];
      u64* d = (u64*)(ringc + (size_t)(t & 3) * 131072 + 65536 + blk * 2048 + lane * 32);
      g_st64(d + 0, v0); g_st64(d + 1, v1); g_st64(d + 2, v2); g_st64(d + 3, v3);
      asm volatile("s_waitcnt vmcnt(0)" ::: "memory");
      __builtin_amdgcn_sched_barrier(0);
      if (lane == 0)
        __hip_atomic_fetch_add(f1, 1, __ATOMIC_RELAXED, __HIP_MEMORY_SCOPE_AGENT);
    }
  }

  // ---- epilogue: out[:, T-1] from h1[T-1] in slot[TSEQ&3] ----
  if (wave == 0) {
    const int* fp = &flags[512 + (lane & 31) * 16];
    while (!__all(g_ld32(fp) >= TSEQ)) __builtin_amdgcn_s_sleep(1);
  }
  __syncthreads();
  stage_one(hB, ringc + (size_t)(TSEQ & 3) * 131072 + 65536, tid);
  __syncthreads();
  if (tid < 256) {
    float od = 0.f;
    #pragma unroll
    for (int j = 0; j < 16; ++j) {
      const int c = (j * 4 + oseg) * 16;
      bf16x8 hv = *(const bf16x8*)(hB + ob * 1024 + (c ^ oxs));
      const float* wo = &wout_s[c >> 1];
      #pragma unroll
      for (int e = 0; e < 8; ++e) od += bf2f((unsigned short)hv[e]) * wo[e];
    }
    od += __shfl_xor(od, 1);
    od += __shfl_xor(od, 2);
    if (oseg == 0) out[ob * TSEQ + (TSEQ - 1)] = od + bout;
  }
}

extern "C" void kernel_launch(void* const* d_in, const int* in_sizes, int n_in,
                              void* d_out, int out_size, void* d_ws, size_t ws_size,
                              hipStream_t stream) {
  (void)in_sizes; (void)n_in; (void)out_size; (void)ws_size;
  const float* x     = (const float*)d_in[0];
  const float* w_in  = (const float*)d_in[1];
  const float* b_in  = (const float*)d_in[2];
  const float* w_ih0 = (const float*)d_in[3];
  const float* w_hh0 = (const float*)d_in[4];
  const float* b_ih0 = (const float*)d_in[5];
  const float* b_hh0 = (const float*)d_in[6];
  const float* w_ih1 = (const float*)d_in[7];
  const float* w_hh1 = (const float*)d_in[8];
  const float* b_ih1 = (const float*)d_in[9];
  const float* b_hh1 = (const float*)d_in[10];
  const float* w_out = (const float*)d_in[11];
  const float* b_out = (const float*)d_in[12];

  char* ws = (char*)d_ws;
  unsigned short* ring = (unsigned short*)(ws + 0);             // 4 * 128KB = 512KB
  float* xg0   = (float*)(ws + 524288);                         // 512KB
  float* h_in  = (float*)(ws + 1048576);                        // 128KB
  int*   flags = (int*)(ws + 1179648);                          // 1024 ints (4KB)

  hipMemsetAsync(flags, 0, 1024 * sizeof(int), stream);
  k_fc_in<<<64, 512, 0, stream>>>(x, w_in, b_in, h_in);
  k_xg0<<<256, 512, 0, stream>>>(h_in, w_ih0, b_ih0, b_hh0, xg0);
  lstm_persist<<<NBLK, 512, 0, stream>>>(w_hh0, w_ih1, w_hh1, b_ih1, b_hh1,
                                         w_out, b_out, xg0, ring,
                                         flags, (float*)d_out);
}

// Round 10
// 5963.320 us; speedup vs baseline: 2.0087x; 1.8716x over previous
//
#include <hip/hip_runtime.h>
#include <stdint.h>

// SingleBandLSTM: B=64, IN=16, H=512, T=1024, 2-layer LSTM, constant input per step.
// R10 = R2 (best passing round, 8.1ms) with ONE change: staging loads are
// wave-coalesced `global_load_dwordx4 ... sc1` in a SINGLE self-contained asm block
// (loads + s_waitcnt vmcnt(0) together; early-clobber outputs -> R4-safe), replacing
// per-lane u64 atomic loads. Theory: sc1 per-lane 8B atomic loads issue ~1 txn/cyc/CU
// = 19.2 GB/s -> 64KB = 3.4us; R2's L1 staged 128KB/step = 6.8us = the step period.
// Coalesced 16B/lane sc1 loads keep LLC coherence (ring slots recycle; L2 is stale)
// but move ~64B/txn -> ~8x fewer transactions.
// Everything else identical to R2: split L0/L1 blocks, RMW flag adds + relaxed polls,
// sc1 h-publishes drained by __syncthreads before flag, ring depths 8.

#define TSEQ 1024
#define HDIM 512
#define BATCH 64
#define RING 8

typedef __attribute__((ext_vector_type(8))) short bf16x8;
typedef __attribute__((ext_vector_type(4))) float f32x4;
typedef __attribute__((ext_vector_type(4))) unsigned int u32x4;

__device__ __forceinline__ unsigned short f2bf(float f) {
  union { float f; unsigned u; } v; v.f = f;
  unsigned r = v.u + 0x7FFFu + ((v.u >> 16) & 1u);   // RNE
  return (unsigned short)(r >> 16);
}
__device__ __forceinline__ float bf2f(unsigned short s) {
  union { unsigned u; float f; } v; v.u = ((unsigned)s) << 16; return v.f;
}
__device__ __forceinline__ float sigm(float x) { return 1.0f / (1.0f + __expf(-x)); }
__device__ __forceinline__ float tanh_(float x) { return 1.0f - 2.0f / (__expf(2.0f * x) + 1.0f); }

__device__ __forceinline__ void flag_add(int* p) {
  __hip_atomic_fetch_add(p, 1, __ATOMIC_RELAXED, __HIP_MEMORY_SCOPE_AGENT);
}
__device__ __forceinline__ void flag_wait(int* p, int target) {
  while (__hip_atomic_load(p, __ATOMIC_RELAXED, __HIP_MEMORY_SCOPE_AGENT) < target)
    __builtin_amdgcn_s_sleep(1);
}

// 64KB global (bf16 [64][512] row-major) -> LDS, XOR swizzle ((row&7)<<4) on byte addr.
// LLC-coherent coalesced loads: 8x dwordx4 sc1 + vmcnt(0) in ONE asm block.
__device__ __forceinline__ void stage64k(char* lds, const unsigned short* src, int tid) {
  u32x4 r0, r1, r2, r3, r4, r5, r6, r7;
  const char* a = (const char*)src + (size_t)tid * 16;
  asm volatile(
      "global_load_dwordx4 %0, %8, off sc1\n\t"
      "global_load_dwordx4 %1, %9, off sc1\n\t"
      "global_load_dwordx4 %2, %10, off sc1\n\t"
      "global_load_dwordx4 %3, %11, off sc1\n\t"
      "global_load_dwordx4 %4, %12, off sc1\n\t"
      "global_load_dwordx4 %5, %13, off sc1\n\t"
      "global_load_dwordx4 %6, %14, off sc1\n\t"
      "global_load_dwordx4 %7, %15, off sc1\n\t"
      "s_waitcnt vmcnt(0)"
      : "=&v"(r0), "=&v"(r1), "=&v"(r2), "=&v"(r3),
        "=&v"(r4), "=&v"(r5), "=&v"(r6), "=&v"(r7)
      : "v"(a), "v"(a + 8192), "v"(a + 16384), "v"(a + 24576),
        "v"(a + 32768), "v"(a + 40960), "v"(a + 49152), "v"(a + 57344)
      : "memory");
  u32x4 vv[8] = {r0, r1, r2, r3, r4, r5, r6, r7};
  #pragma unroll
  for (int i = 0; i < 8; ++i) {
    int q = tid + i * 512;
    int row = q >> 6, kb = (q & 63) << 4;
    *(u32x4*)(lds + row * 1024 + (kb ^ ((row & 7) << 4))) = vv[i];
  }
}
__device__ __forceinline__ void zero64k(char* lds, int tid) {
  u32x4 z = {0u, 0u, 0u, 0u};
  #pragma unroll
  for (int i = 0; i < 8; ++i) {
    int q = tid + i * 512;
    int row = q >> 6, kb = (q & 63) << 4;
    *(u32x4*)(lds + row * 1024 + (kb ^ ((row & 7) << 4))) = z;
  }
}

// ---------------- precompute kernels ----------------
__global__ void k_fc_in(const float* __restrict__ x, const float* __restrict__ w_in,
                        const float* __restrict__ b_in, float* __restrict__ h_in) {
  int b = blockIdx.x;      // 64
  int j = threadIdx.x;     // 512
  float acc = b_in[j];
  #pragma unroll
  for (int i = 0; i < 16; ++i) acc += x[b * 16 + i] * w_in[j * 16 + i];
  h_in[b * HDIM + j] = acc;
}

__global__ __launch_bounds__(512, 1)
void k_xg0(const float* __restrict__ h_in, const float* __restrict__ w_ih0,
           const float* __restrict__ b_ih0, const float* __restrict__ b_hh0,
           float* __restrict__ xg0) {
  __shared__ float hbuf[64 * 516];
  __shared__ float wbuf[8 * 520];
  int r0 = blockIdx.x * 8;           // 256 blocks x 8 rows = 2048 gate rows
  int tid = threadIdx.x;
  for (int i = 0; i < 64; ++i) {
    int c = tid + i * 512;
    hbuf[(c >> 9) * 516 + (c & 511)] = h_in[c];
  }
  for (int i = 0; i < 8; ++i) {
    int c = tid + i * 512;
    wbuf[(c >> 9) * 520 + (c & 511)] = w_ih0[(size_t)r0 * HDIM + c];
  }
  __syncthreads();
  int b = tid >> 3, rl = tid & 7;
  float acc = 0.f;
  for (int k = 0; k < 512; ++k) acc += hbuf[b * 516 + k] * wbuf[rl * 520 + k];
  int r = r0 + rl;
  xg0[(size_t)b * 2048 + r] = acc + b_ih0[r] + b_hh0[r];
}

// ---------------- persistent recurrence kernel ----------------
__global__ __launch_bounds__(512, 1)
void lstm_persist(const float* __restrict__ w_hh0,
                  const float* __restrict__ w_ih1,
                  const float* __restrict__ w_hh1,
                  const float* __restrict__ b_ih1,
                  const float* __restrict__ b_hh1,
                  const float* __restrict__ w_out,
                  const float* __restrict__ b_out,
                  const float* __restrict__ xg0,
                  unsigned short* __restrict__ h0_ring,
                  unsigned short* __restrict__ h1_ring,
                  int* __restrict__ flags,
                  float* __restrict__ out) {
  __shared__ __align__(16) unsigned short hA[BATCH * HDIM];  // 64KB, swizzled
  __shared__ __align__(16) unsigned short hBt[BATCH * HDIM]; // 64KB, swizzled (L1: h1 tile)
  __shared__ float gbuf[BATCH * 68];                         // gate transpose buffer
  char* hAc = (char*)hA;
  char* hBc = (char*)hBt;

  const int tid = threadIdx.x;
  const int layer = blockIdx.x & 1;
  const int p = blockIdx.x >> 1;      // 0..31 within group
  const int u0 = p * 16;              // first owned hidden unit

  const int wave = tid >> 6, lane = tid & 63;
  const int nt = wave & 3;            // N-tile (16 gate rows)
  const int mh = wave >> 2;           // M-tile pair selector
  const int ln15 = lane & 15, lg = lane >> 4;

  // slice row ordering: n_local = unit_local*4 + gate  (gate: 0=i,1=f,2=g,3=o)
  const int n_local = nt * 16 + ln15;
  const int grow = (n_local & 3) * HDIM + u0 + (n_local >> 2);  // global gate row

  int* h0_ready = flags;
  int* h0_done  = flags + TSEQ;
  int* h1_ready = flags + 2 * TSEQ;
  int* h1_done  = flags + 3 * TSEQ;

  // ---- weight fragments into registers (fp32 -> bf16) ----
  bf16x8 wh[16];  // w_hh (layer 0 or 1)
  bf16x8 wi[16];  // w_ih1 (layer 1 only)
  {
    const float* Wh = (layer == 0 ? w_hh0 : w_hh1) + (size_t)grow * HDIM;
    #pragma unroll
    for (int kt = 0; kt < 16; ++kt) {
      const float* s = Wh + kt * 32 + lg * 8;
      bf16x8 r;
      #pragma unroll
      for (int e = 0; e < 8; ++e) r[e] = (short)f2bf(s[e]);
      wh[kt] = r;
    }
  }
  if (layer == 1) {
    const float* Wi = w_ih1 + (size_t)grow * HDIM;
    #pragma unroll
    for (int kt = 0; kt < 16; ++kt) {
      const float* s = Wi + kt * 32 + lg * 8;
      bf16x8 r;
      #pragma unroll
      for (int e = 0; e < 8; ++e) r[e] = (short)f2bf(s[e]);
      wi[kt] = r;
    }
  }

  // ---- accumulator init (xg0 fragment for L0; bias for L1) ----
  f32x4 init0, init1;
  if (layer == 0) {
    #pragma unroll
    for (int r = 0; r < 4; ++r) {
      init0[r] = xg0[(size_t)(mh * 32 + lg * 4 + r) * 2048 + grow];
      init1[r] = xg0[(size_t)(mh * 32 + 16 + lg * 4 + r) * 2048 + grow];
    }
  } else {
    float bv = b_ih1[grow] + b_hh1[grow];
    #pragma unroll
    for (int r = 0; r < 4; ++r) { init0[r] = bv; init1[r] = bv; }
  }

  // cell state for this thread's two (batch,unit) pairs
  float c0 = 0.f, c1 = 0.f;
  const int pb = tid >> 3;            // batch of pair
  const int pu = (tid << 1) & 15;     // unit_local (even)

  const int r0 = mh * 32 + ln15, r1 = r0 + 16;
  const int x0 = (r0 & 7) << 4, x1 = (r1 & 7) << 4;

  if (layer == 0) {
    for (int t = 0; t < TSEQ; ++t) {
      if (t > 0) {
        if (tid == 0) flag_wait(&h0_ready[t - 1], 32);
        __syncthreads();
        stage64k(hAc, h0_ring + (size_t)((t - 1) & (RING - 1)) * (BATCH * HDIM), tid);
        __syncthreads();
        if (tid == 0) flag_add(&h0_done[t - 1]);
      } else {
        zero64k(hAc, tid);
        __syncthreads();
      }
      f32x4 a0 = init0, a1 = init1;
      #pragma unroll
      for (int kt = 0; kt < 16; ++kt) {
        const int kb = kt * 64 + lg * 16;
        bf16x8 ha0 = *(const bf16x8*)(hAc + r0 * 1024 + (kb ^ x0));
        bf16x8 ha1 = *(const bf16x8*)(hAc + r1 * 1024 + (kb ^ x1));
        a0 = __builtin_amdgcn_mfma_f32_16x16x32_bf16(ha0, wh[kt], a0, 0, 0, 0);
        a1 = __builtin_amdgcn_mfma_f32_16x16x32_bf16(ha1, wh[kt], a1, 0, 0, 0);
      }
      #pragma unroll
      for (int r = 0; r < 4; ++r) {
        gbuf[(mh * 32 + lg * 4 + r) * 68 + n_local] = a0[r];
        gbuf[(mh * 32 + 16 + lg * 4 + r) * 68 + n_local] = a1[r];
      }
      if (t >= RING && tid == 0) flag_wait(&h0_done[t - RING], 64);
      __syncthreads();
      {
        f32x4 gA = *(const f32x4*)&gbuf[pb * 68 + pu * 4];
        f32x4 gB = *(const f32x4*)&gbuf[pb * 68 + pu * 4 + 4];
        float i0 = sigm(gA[0]), f0 = sigm(gA[1]), z0 = tanh_(gA[2]), o0 = sigm(gA[3]);
        float i1 = sigm(gB[0]), f1 = sigm(gB[1]), z1 = tanh_(gB[2]), o1 = sigm(gB[3]);
        c0 = f0 * c0 + i0 * z0;
        c1 = f1 * c1 + i1 * z1;
        float hv0 = o0 * tanh_(c0), hv1 = o1 * tanh_(c1);
        unsigned pk = (unsigned)f2bf(hv0) | ((unsigned)f2bf(hv1) << 16);
        unsigned short* slot = h0_ring + (size_t)(t & (RING - 1)) * (BATCH * HDIM);
        __hip_atomic_store((unsigned*)(slot + pb * HDIM + u0 + pu), pk,
                           __ATOMIC_RELAXED, __HIP_MEMORY_SCOPE_AGENT);
      }
      __syncthreads();   // implicit vmcnt(0): all sc1 h-stores visible at LLC
      if (tid == 0) flag_add(&h0_ready[t]);
    }
  } else {
    for (int t = 0; t < TSEQ; ++t) {
      // --- poll both producers, stage both tiles, one barrier pair ---
      if (tid == 0) {
        flag_wait(&h0_ready[t], 32);
        if (t > 0) flag_wait(&h1_ready[t - 1], 32);
      }
      __syncthreads();
      stage64k(hAc, h0_ring + (size_t)(t & (RING - 1)) * (BATCH * HDIM), tid);
      if (t > 0)
        stage64k(hBc, h1_ring + (size_t)((t - 1) & (RING - 1)) * (BATCH * HDIM), tid);
      else
        zero64k(hBc, tid);
      __syncthreads();
      if (tid == 0) {
        flag_add(&h0_done[t]);
        if (t > 0) flag_add(&h1_done[t - 1]);
      }

      // --- out_{t-1} from h1 tile (16 threads of wave 0; other waves proceed) ---
      if (t > 0 && tid < 16) {
        const int b = 2 * p + (tid >> 3), seg = tid & 7;
        const int xb = (b & 7) << 4;
        float acc = 0.f;
        #pragma unroll
        for (int i = 0; i < 8; ++i) {
          const int kb = seg * 128 + i * 16;
          bf16x8 hv = *(const bf16x8*)(hBc + b * 1024 + (kb ^ xb));
          const float* wo = w_out + (kb >> 1);
          #pragma unroll
          for (int e = 0; e < 8; ++e) acc += bf2f((unsigned short)hv[e]) * wo[e];
        }
        acc += __shfl_down(acc, 4, 8);
        acc += __shfl_down(acc, 2, 8);
        acc += __shfl_down(acc, 1, 8);
        if (seg == 0) out[b * TSEQ + (t - 1)] = acc + b_out[0];
      }

      // --- fused ih (from h0 tile) + hh (from h1 tile) MFMA loop ---
      f32x4 a0 = init0, a1 = init1;
      #pragma unroll
      for (int kt = 0; kt < 16; ++kt) {
        const int kb = kt * 64 + lg * 16;
        bf16x8 ia0 = *(const bf16x8*)(hAc + r0 * 1024 + (kb ^ x0));
        bf16x8 ia1 = *(const bf16x8*)(hAc + r1 * 1024 + (kb ^ x1));
        bf16x8 ha0 = *(const bf16x8*)(hBc + r0 * 1024 + (kb ^ x0));
        bf16x8 ha1 = *(const bf16x8*)(hBc + r1 * 1024 + (kb ^ x1));
        a0 = __builtin_amdgcn_mfma_f32_16x16x32_bf16(ia0, wi[kt], a0, 0, 0, 0);
        a1 = __builtin_amdgcn_mfma_f32_16x16x32_bf16(ia1, wi[kt], a1, 0, 0, 0);
        a0 = __builtin_amdgcn_mfma_f32_16x16x32_bf16(ha0, wh[kt], a0, 0, 0, 0);
        a1 = __builtin_amdgcn_mfma_f32_16x16x32_bf16(ha1, wh[kt], a1, 0, 0, 0);
      }
      #pragma unroll
      for (int r = 0; r < 4; ++r) {
        gbuf[(mh * 32 + lg * 4 + r) * 68 + n_local] = a0[r];
        gbuf[(mh * 32 + 16 + lg * 4 + r) * 68 + n_local] = a1[r];
      }
      if (t >= RING && tid == 0) flag_wait(&h1_done[t - RING], 32);
      __syncthreads();
      {
        f32x4 gA = *(const f32x4*)&gbuf[pb * 68 + pu * 4];
        f32x4 gB = *(const f32x4*)&gbuf[pb * 68 + pu * 4 + 4];
        float i0 = sigm(gA[0]), f0 = sigm(gA[1]), z0 = tanh_(gA[2]), o0 = sigm(gA[3]);
        float i1 = sigm(gB[0]), f1 = sigm(gB[1]), z1 = tanh_(gB[2]), o1 = sigm(gB[3]);
        c0 = f0 * c0 + i0 * z0;
        c1 = f1 * c1 + i1 * z1;
        float hv0 = o0 * tanh_(c0), hv1 = o1 * tanh_(c1);
        unsigned pk = (unsigned)f2bf(hv0) | ((unsigned)f2bf(hv1) << 16);
        unsigned short* slot = h1_ring + (size_t)(t & (RING - 1)) * (BATCH * HDIM);
        __hip_atomic_store((unsigned*)(slot + pb * HDIM + u0 + pu), pk,
                           __ATOMIC_RELAXED, __HIP_MEMORY_SCOPE_AGENT);
      }
      __syncthreads();   // implicit vmcnt(0): all sc1 h-stores visible at LLC
      if (tid == 0) flag_add(&h1_ready[t]);
    }
    // epilogue: out_{T-1}
    if (tid == 0) flag_wait(&h1_ready[TSEQ - 1], 32);
    __syncthreads();
    stage64k(hBc, h1_ring + (size_t)((TSEQ - 1) & (RING - 1)) * (BATCH * HDIM), tid);
    __syncthreads();
    if (tid < 16) {
      const int b = 2 * p + (tid >> 3), seg = tid & 7;
      const int xb = (b & 7) << 4;
      float acc = 0.f;
      #pragma unroll
      for (int i = 0; i < 8; ++i) {
        const int kb = seg * 128 + i * 16;
        bf16x8 hv = *(const bf16x8*)(hBc + b * 1024 + (kb ^ xb));
        const float* wo = w_out + (kb >> 1);
        #pragma unroll
        for (int e = 0; e < 8; ++e) acc += bf2f((unsigned short)hv[e]) * wo[e];
      }
      acc += __shfl_down(acc, 4, 8);
      acc += __shfl_down(acc, 2, 8);
      acc += __shfl_down(acc, 1, 8);
      if (seg == 0) out[b * TSEQ + (TSEQ - 1)] = acc + b_out[0];
    }
  }
}

extern "C" void kernel_launch(void* const* d_in, const int* in_sizes, int n_in,
                              void* d_out, int out_size, void* d_ws, size_t ws_size,
                              hipStream_t stream) {
  (void)in_sizes; (void)n_in; (void)out_size; (void)ws_size;
  const float* x     = (const float*)d_in[0];
  const float* w_in  = (const float*)d_in[1];
  const float* b_in  = (const float*)d_in[2];
  const float* w_ih0 = (const float*)d_in[3];
  const float* w_hh0 = (const float*)d_in[4];
  const float* b_ih0 = (const float*)d_in[5];
  const float* b_hh0 = (const float*)d_in[6];
  const float* w_ih1 = (const float*)d_in[7];
  const float* w_hh1 = (const float*)d_in[8];
  const float* b_ih1 = (const float*)d_in[9];
  const float* b_hh1 = (const float*)d_in[10];
  const float* w_out = (const float*)d_in[11];
  const float* b_out = (const float*)d_in[12];

  char* ws = (char*)d_ws;
  unsigned short* h0_ring = (unsigned short*)(ws + 0);          // 512KB
  unsigned short* h1_ring = (unsigned short*)(ws + 524288);     // 512KB
  float* xg0  = (float*)(ws + 1048576);                         // 512KB
  float* h_in = (float*)(ws + 1572864);                         // 128KB
  int*   flags = (int*)(ws + 1703936);                          // 16KB

  hipMemsetAsync(flags, 0, 4 * TSEQ * sizeof(int), stream);
  k_fc_in<<<64, 512, 0, stream>>>(x, w_in, b_in, h_in);
  k_xg0<<<256, 512, 0, stream>>>(h_in, w_ih0, b_ih0, b_hh0, xg0);
  lstm_persist<<<64, 512, 0, stream>>>(w_hh0, w_ih1, w_hh1, b_ih1, b_hh1,
                                       w_out, b_out, xg0, h0_ring, h1_ring,
                                       flags, (float*)d_out);
}